// Round 4
// baseline (141.194 us; speedup 1.0000x reference)
//
#include <hip/hip_runtime.h>

#define T_SEQ 4096
#define NH    12

typedef _Float16 half8  __attribute__((ext_vector_type(8)));
typedef _Float16 half4  __attribute__((ext_vector_type(4)));
typedef float    floatx4 __attribute__((ext_vector_type(4)));

// Sliding-window attention, window [gq-128, gq+128) ∩ [0,T).
// One WG = 128 query rows; 8 waves * 16 rows; grid = 768 = exactly 3 WG/CU
// (48 KB LDS * 3 = 144 KB/CU; __launch_bounds__(512,6) -> 84-reg cap).
// REGISTER-FIT REWORK vs round 3 (which spilled: WRITE 41.5 MiB vs 24 MiB
// output, VGPR=40):
//  * QK^T computed in TWO half-passes (acc[2] each) -> accum peak 24 not 32.
//  * Staging split write-early/convert-late: f16 slot (8 regs) lives across
//    the barrier; the 16 f32 prefetch regs die the same iteration (convert
//    right after compute; vmcnt wait covered by compute).
// Swapped QK^T (mfma(K,Q) -> S^T): P written as 4x ds_write_b64. Row-sum
// fused into exp pass. Rolled main loop. Plane-grouped XCD map. Raw barrier
// (lgkmcnt only, NO vmcnt drain, T4). setprio(1) around MFMA (T5).
__global__ __launch_bounds__(512, 6) void local_attn_f16(
    const float* __restrict__ Qg, const float* __restrict__ Kg,
    const float* __restrict__ Vg, float* __restrict__ Og)
{
    // XOR-swizzled 16B-block layouts: element (row,x) at
    // row*64 + (((x>>3) ^ (row&7))*8) + (x&7)   [halves]
    __shared__ _Float16 Ks[2][64 * 64];  // K chunk  [key][d]
    __shared__ _Float16 Vt[2][64 * 64];  // V^T      [d][key]
    __shared__ _Float16 Ps[8][16 * 64];  // per-wave P [qrow][key]

    const int t    = threadIdx.x;
    const int w    = t >> 6;        // wave id 0..7
    const int lane = t & 63;
    const int n    = lane & 15;     // MFMA 16-index
    const int qd   = lane >> 4;     // quad 0..3

    // Plane-grouped XCD mapping: wgid%8 == bx&7 (gridX=32). XCD j owns
    // planes 3j..3j+2 (6 MB K/V set vs 9.2 MB naive) for L2 locality.
    const int bx = blockIdx.x;                    // 0..31
    const int u  = blockIdx.y + NH * blockIdx.z;  // 0..23
    const int plane = 3 * (bx & 7) + (u >> 3);    // 0..23
    const int tile  = (bx >> 3) + 4 * (u & 7);    // 0..31
    const int s     = tile << 7;                  // query tile start (128 rows)
    const size_t planeoff = (size_t)plane * (size_t)(T_SEQ * 64);

    const float* Qp = Qg + planeoff;
    const float* Kp = Kg + planeoff;
    const float* Vp = Vg + planeoff;
    float*       Op = Og + planeoff;

    // staging thread mappings (64-key chunk staged by all 512 threads)
    const int kr  = t >> 3;         // K row 0..63
    const int kbi = t & 7;          // 8-float block within row
    const int vd  = t & 63;         // V^T: this thread owns column d
    const int vjb = t >> 6;         // 8-key range per wave

    // ---- staging state ----
    floatx4 kp0, kp1;               // f32 in flight (dies each iteration)
    float   vp[8];
    half8   hk, hv;                 // converted slot (lives across barrier)

    auto prefetchKV = [&](int c) {  // issue 10 loads, no wait
        const int gk0 = s - 128 + 64 * c;
        const float* kb = Kp + (size_t)(gk0 + kr) * 64 + kbi * 8;
        kp0 = *(const floatx4*)kb;
        kp1 = *(const floatx4*)(kb + 4);
        const float* vb = Vp + (size_t)(gk0 + vjb * 8) * 64 + vd;
        #pragma unroll
        for (int j = 0; j < 8; ++j)          // 8x coalesced 256B/wave
            vp[j] = vb[(size_t)j * 64];
    };

    auto convertKV = [&]() {        // counted vmcnt waits inserted by compiler
        #pragma unroll
        for (int i = 0; i < 4; ++i) {
            hk[i]     = (_Float16)kp0[i];
            hk[i + 4] = (_Float16)kp1[i];
        }
        #pragma unroll
        for (int i = 0; i < 8; ++i)
            hv[i] = (_Float16)vp[i];
    };

    auto writeKV = [&](int buf) {   // pure ds_write of the f16 slot
        *(half8*)&Ks[buf][kr * 64 + (kbi ^ (kr & 7)) * 8] = hk;
        *(half8*)&Vt[buf][vd * 64 + (vjb ^ (vd & 7)) * 8] = hv;
    };

    const int cbeg = (s == 0) ? 2 : 0;
    const int cend = (s == T_SEQ - 128) ? 3 : 5;

    // ---- prologue part 1: first chunk's loads in flight, then build Q ----
    prefetchKV(cbeg);
    half8 qf[2];
    {
        const float* qptr = Qp + (size_t)(s + 16 * w + n) * 64 + qd * 8;
        const float qscale = 0.125f * 1.44269504088896340736f;
        #pragma unroll
        for (int ks = 0; ks < 2; ++ks) {
            floatx4 a = *(const floatx4*)(qptr + 32 * ks);
            floatx4 b = *(const floatx4*)(qptr + 32 * ks + 4);
            half8 h;
            #pragma unroll
            for (int i = 0; i < 4; ++i) {
                h[i]     = (_Float16)(a[i] * qscale);
                h[i + 4] = (_Float16)(b[i] * qscale);
            }
            qf[ks] = h;
        }
    }

    floatx4 Oacc[4] = {{0.f,0.f,0.f,0.f},{0.f,0.f,0.f,0.f},
                       {0.f,0.f,0.f,0.f},{0.f,0.f,0.f,0.f}};
    float Lsum = 0.f;

    // Raw barrier: publish LDS writes, do NOT drain vmcnt (T4).
    #define WG_BARRIER() do {                                        \
        __builtin_amdgcn_sched_barrier(0);                           \
        asm volatile("s_waitcnt lgkmcnt(0)" ::: "memory");           \
        __builtin_amdgcn_s_barrier();                                \
        __builtin_amdgcn_sched_barrier(0);                           \
    } while (0)

    _Float16* Pw = &Ps[w][0];

    auto compute = [&](int buf, int c) {
        const int wbase = 16 * w;
        // wave-uniform full-mask skip: waves 4-7 skip c=0, waves 0-3 skip c=5
        if (64 * c + 63 < wbase || 64 * c >= wbase + 271) return;

        const int  qloc   = wbase + n;
        const bool loEdge = (64 * c < wbase + 16);
        const bool hiEdge = (64 * c >= wbase + 193);
        const int  tLo    = qloc - 64 * c;        // kk <  tLo -> invalid
        const int  tHi    = qloc + 256 - 64 * c;  // kk >= tHi -> invalid

        // ---- S^T = K (Q*log2e)^T in TWO half-passes (acc peak = 8 regs) ----
        #pragma unroll
        for (int h = 0; h < 2; ++h) {
            floatx4 a0 = {0.f,0.f,0.f,0.f}, a1 = {0.f,0.f,0.f,0.f};
            const int key0 = (2 * h) * 16 + n;
            const int key1 = (2 * h + 1) * 16 + n;
            __builtin_amdgcn_s_setprio(1);
            #pragma unroll
            for (int ks = 0; ks < 2; ++ks) {
                half8 kf0 = *(const half8*)&Ks[buf][key0 * 64 + (((ks << 2) | qd) ^ (key0 & 7)) * 8];
                half8 kf1 = *(const half8*)&Ks[buf][key1 * 64 + (((ks << 2) | qd) ^ (key1 & 7)) * 8];
                a0 = __builtin_amdgcn_mfma_f32_16x16x32_f16(kf0, qf[ks], a0, 0, 0, 0);
                a1 = __builtin_amdgcn_mfma_f32_16x16x32_f16(kf1, qf[ks], a1, 0, 0, 0);
            }
            __builtin_amdgcn_s_setprio(0);

            // masks + exp + pack for tt = 2h, 2h+1
            #pragma unroll
            for (int tti = 0; tti < 2; ++tti) {
                const int tt = 2 * h + tti;
                floatx4 av = tti ? a1 : a0;
                if (loEdge) {
                    #pragma unroll
                    for (int rg = 0; rg < 4; ++rg)
                        if (tt * 16 + qd * 4 + rg < tLo) av[rg] = -1e30f;
                }
                if (hiEdge) {
                    #pragma unroll
                    for (int rg = 0; rg < 4; ++rg)
                        if (tt * 16 + qd * 4 + rg >= tHi) av[rg] = -1e30f;
                }
                float p0, p1, p2, p3;
                asm("v_exp_f32 %0, %1" : "=v"(p0) : "v"(av[0]));
                asm("v_exp_f32 %0, %1" : "=v"(p1) : "v"(av[1]));
                asm("v_exp_f32 %0, %1" : "=v"(p2) : "v"(av[2]));
                asm("v_exp_f32 %0, %1" : "=v"(p3) : "v"(av[3]));
                Lsum += (p0 + p1) + (p2 + p3);
                half4 pk;
                pk[0] = (_Float16)p0; pk[1] = (_Float16)p1;
                pk[2] = (_Float16)p2; pk[3] = (_Float16)p3;
                // keys 16tt+4qd..+3, query n: contiguous 8B (block 2tt+(qd>>1))
                *(half4*)&Pw[n * 64 + ((2 * tt + (qd >> 1)) ^ (n & 7)) * 8 + (qd & 1) * 4] = pk;
            }
        }

        // Ps is per-wave: drain DS writes only, no WG barrier.
        asm volatile("s_waitcnt lgkmcnt(0)" ::: "memory");

        // ---- O += P V ----
        __builtin_amdgcn_s_setprio(1);
        #pragma unroll
        for (int js = 0; js < 2; ++js) {
            half8 pf = *(const half8*)&Pw[n * 64 + (((js << 2) | qd) ^ (n & 7)) * 8];
            #pragma unroll
            for (int tt = 0; tt < 4; ++tt) {
                const int d = tt * 16 + n;
                half8 vf = *(const half8*)&Vt[buf][d * 64 + (((js << 2) | qd) ^ (d & 7)) * 8];
                Oacc[tt] = __builtin_amdgcn_mfma_f32_16x16x32_f16(pf, vf, Oacc[tt], 0, 0, 0);
            }
        }
        __builtin_amdgcn_s_setprio(0);
    };

    // ---- prologue part 2 ----
    convertKV();                // hk/hv = chunk cbeg
    writeKV(0);                 // LDS buf0 <- cbeg
    prefetchKV(cbeg + 1);
    convertKV();                // hk/hv = cbeg+1 (one exposed wait per WG)
    WG_BARRIER();               // publish buf0

    // ---- rolled main loop; invariant at top: hk/hv = chunk c+1 ----
    int cur = 0;
    #pragma unroll 1
    for (int c = cbeg; c <= cend; ++c) {
        if (c + 1 <= cend) writeKV(1 - cur);   // ds_write only
        if (c + 2 <= cend) prefetchKV(c + 2);  // issue; in flight over compute
        compute(cur, c);
        if (c + 2 <= cend) convertKV();        // counted wait; f32 regs die here
        if (c < cend) WG_BARRIER();            // publish buf[1-cur]
        cur ^= 1;
    }

    // ---- epilogue: reduce l across quads, divide, store fp32 ----
    float lt = Lsum + __shfl_xor(Lsum, 16, 64);
    lt += __shfl_xor(lt, 32, 64);              // lanes with same n: full sum for query n
    #pragma unroll
    for (int rg = 0; rg < 4; ++rg) {
        const float lr = __shfl(lt, qd * 4 + rg, 64);  // L for this output row
        const float inv = 1.0f / lr;
        float* op = Op + (size_t)(s + 16 * w + qd * 4 + rg) * 64 + n;
        op[0]  = Oacc[0][rg] * inv;
        op[16] = Oacc[1][rg] * inv;
        op[32] = Oacc[2][rg] * inv;
        op[48] = Oacc[3][rg] * inv;
    }
}

extern "C" void kernel_launch(void* const* d_in, const int* in_sizes, int n_in,
                              void* d_out, int out_size, void* d_ws, size_t ws_size,
                              hipStream_t stream) {
    const float* q = (const float*)d_in[0];
    const float* k = (const float*)d_in[1];
    const float* v = (const float*)d_in[2];
    float* o = (float*)d_out;
    dim3 grid(T_SEQ / 128, NH, 2);
    dim3 block(512);
    local_attn_f16<<<grid, block, 0, stream>>>(q, k, v, o);
}

// Round 5
// 117.288 us; speedup vs baseline: 1.2038x; 1.2038x over previous
//
#include <hip/hip_runtime.h>

#define T_SEQ 4096
#define NH    12

typedef _Float16 half8  __attribute__((ext_vector_type(8)));
typedef _Float16 half4  __attribute__((ext_vector_type(4)));
typedef float    floatx4 __attribute__((ext_vector_type(4)));

// Sliding-window attention, window [gq-128, gq+128) ∩ [0,T).
// REVERT to the proven 4-wave/64-row structure (round 1: <41.5us, no spill),
// then raise occupancy via LDS: SINGLE-buffered K/V + per-wave Ps = 24 KB
// -> 6 WG/CU, and grid 1536 = EXACTLY 6 WG/CU (one clean round, no tail).
// Single-buffer costs 2 barriers/chunk; 6 co-resident WGs/CU hide it (TLP).
// Register-neutral wins kept from r2-4 (all harness-verified): swapped QK^T
// (mfma(K,Q) -> S^T, P written as 4x ds_write_b64), fused row-sum (no
// ones-MFMA), v_exp_f32 with log2e folded into Q scale, setprio(1) around
// MFMA, plane-grouped XCD map. Barriers drain lgkmcnt ONLY (T4): chunk c+1
// global loads issue before compute(c) and stay in flight across it.
// Plain __launch_bounds__(256): the (512,6) min-waves cap caused the
// allocator to spill (VGPR=40, WRITE 2x output) in rounds 2-4.
__global__ __launch_bounds__(256) void local_attn_f16(
    const float* __restrict__ Qg, const float* __restrict__ Kg,
    const float* __restrict__ Vg, float* __restrict__ Og)
{
    // XOR-swizzled 16B-block layouts: element (row,x) at
    // row*64 + (((x>>3) ^ (row&7))*8) + (x&7)   [halves]
    __shared__ _Float16 Ks[64 * 64];     // K chunk  [key][d]   (single buf)
    __shared__ _Float16 Vt[64 * 64];     // V^T      [d][key]   (single buf)
    __shared__ _Float16 Ps[4][16 * 64];  // per-wave P [qrow][key]

    const int t    = threadIdx.x;
    const int w    = t >> 6;        // wave id 0..3
    const int lane = t & 63;
    const int n    = lane & 15;     // MFMA 16-index (query col of S^T)
    const int qd   = lane >> 4;     // quad 0..3

    // Plane-grouped XCD map: wgid%8 == bx&7 (gridX=64). XCD j owns planes
    // 3j..3j+2; within an XCD, adjacent tiles are temporally adjacent.
    const int bx = blockIdx.x;                    // 0..63
    const int u  = blockIdx.y + NH * blockIdx.z;  // 0..23
    const int plane = 3 * (bx & 7) + (u >> 3);    // 0..23
    const int tile  = (bx >> 3) + 8 * (u & 7);    // 0..63
    const int s     = tile << 6;                  // query tile start (64 rows)
    const size_t planeoff = (size_t)plane * (size_t)(T_SEQ * 64);

    const float* Qp = Qg + planeoff;
    const float* Kp = Kg + planeoff;
    const float* Vp = Vg + planeoff;
    float*       Op = Og + planeoff;

    // staging thread mappings (64-key chunk staged by all 256 threads)
    const int kr0 = t >> 3;          // K rows 0..31
    const int kr1 = 32 + (t >> 3);   // K rows 32..63
    const int kbi = t & 7;           // 8-float block within row
    const int vd  = t & 63;          // V^T: this thread owns column d
    const int vjb = t >> 6;          // 16-key range per wave

    // ---- single prefetch slot (32 f32 regs, live across one compute) ----
    floatx4 kp0, kp1, kp2, kp3;
    float   vp[16];

    auto prefetchKV = [&](int c) {   // issue 20 loads, no wait
        const int gk0 = s - 128 + 64 * c;
        const float* kb = Kp + (size_t)gk0 * 64 + kbi * 8;
        kp0 = *(const floatx4*)(kb + (size_t)kr0 * 64);
        kp1 = *(const floatx4*)(kb + (size_t)kr0 * 64 + 4);
        kp2 = *(const floatx4*)(kb + (size_t)kr1 * 64);
        kp3 = *(const floatx4*)(kb + (size_t)kr1 * 64 + 4);
        const float* vb = Vp + (size_t)(gk0 + vjb * 16) * 64 + vd;
        #pragma unroll
        for (int j = 0; j < 16; ++j)         // coalesced 256B/wave each
            vp[j] = vb[(size_t)j * 64];
    };

    auto commitKV = [&]() {          // counted vmcnt waits, convert, ds_write
        half8 h0, h1, v0, v1;
        #pragma unroll
        for (int i = 0; i < 4; ++i) {
            h0[i] = (_Float16)kp0[i]; h0[i + 4] = (_Float16)kp1[i];
            h1[i] = (_Float16)kp2[i]; h1[i + 4] = (_Float16)kp3[i];
        }
        #pragma unroll
        for (int i = 0; i < 8; ++i) {
            v0[i] = (_Float16)vp[i];
            v1[i] = (_Float16)vp[8 + i];
        }
        *(half8*)&Ks[kr0 * 64 + (kbi ^ (kr0 & 7)) * 8] = h0;
        *(half8*)&Ks[kr1 * 64 + (kbi ^ (kr1 & 7)) * 8] = h1;
        *(half8*)&Vt[vd * 64 + ((2 * vjb)     ^ (vd & 7)) * 8] = v0;
        *(half8*)&Vt[vd * 64 + ((2 * vjb + 1) ^ (vd & 7)) * 8] = v1;
    };

    const int cbeg = (s == 0) ? 2 : (s == 64) ? 1 : 0;
    const int cend = (s == T_SEQ - 64) ? 2 : (s == T_SEQ - 128) ? 3 : 4;

    // ---- prologue: chunk cbeg loads in flight while Q fragments build ----
    prefetchKV(cbeg);
    half8 qf[2];
    {
        const float* qptr = Qp + (size_t)(s + 16 * w + n) * 64 + qd * 8;
        const float qscale = 0.125f * 1.44269504088896340736f;  // /sqrt(64)*log2e
        #pragma unroll
        for (int ks = 0; ks < 2; ++ks) {
            floatx4 a = *(const floatx4*)(qptr + 32 * ks);
            floatx4 b = *(const floatx4*)(qptr + 32 * ks + 4);
            half8 h;
            #pragma unroll
            for (int i = 0; i < 4; ++i) {
                h[i]     = (_Float16)(a[i] * qscale);
                h[i + 4] = (_Float16)(b[i] * qscale);
            }
            qf[ks] = h;
        }
    }

    floatx4 Oacc[4] = {{0.f,0.f,0.f,0.f},{0.f,0.f,0.f,0.f},
                       {0.f,0.f,0.f,0.f},{0.f,0.f,0.f,0.f}};
    float Lsum = 0.f;

    // Raw barrier: publish LDS writes, do NOT drain vmcnt (T4).
    #define WG_BARRIER() do {                                        \
        __builtin_amdgcn_sched_barrier(0);                           \
        asm volatile("s_waitcnt lgkmcnt(0)" ::: "memory");           \
        __builtin_amdgcn_s_barrier();                                \
        __builtin_amdgcn_sched_barrier(0);                           \
    } while (0)

    _Float16* Pw = &Ps[w][0];

    auto compute = [&](int c) {
        // ---- S^T = K (Q*log2e)^T : 8 MFMAs; S^T[key=16tt+4qd+rg][query=n] ----
        floatx4 acc[4] = {{0.f,0.f,0.f,0.f},{0.f,0.f,0.f,0.f},
                          {0.f,0.f,0.f,0.f},{0.f,0.f,0.f,0.f}};
        __builtin_amdgcn_s_setprio(1);
        #pragma unroll
        for (int ks = 0; ks < 2; ++ks) {
            #pragma unroll
            for (int tt = 0; tt < 4; ++tt) {
                const int key = tt * 16 + n;
                half8 kf = *(const half8*)&Ks[key * 64 + (((ks << 2) | qd) ^ (key & 7)) * 8];
                acc[tt] = __builtin_amdgcn_mfma_f32_16x16x32_f16(kf, qf[ks], acc[tt], 0, 0, 0);
            }
        }
        __builtin_amdgcn_s_setprio(0);

        // ---- window masks (key kk valid iff 0 <= 64c+kk-qloc < 256):
        // lower edge only at c==0 (kk < qloc), upper only at c==4 (kk >= qloc)
        const int qloc = 16 * w + n;
        if (c == 0) {
            #pragma unroll
            for (int tt = 0; tt < 4; ++tt)
                #pragma unroll
                for (int rg = 0; rg < 4; ++rg)
                    if (tt * 16 + qd * 4 + rg < qloc) acc[tt][rg] = -1e30f;
        } else if (c == 4) {
            #pragma unroll
            for (int tt = 0; tt < 4; ++tt)
                #pragma unroll
                for (int rg = 0; rg < 4; ++rg)
                    if (tt * 16 + qd * 4 + rg >= qloc) acc[tt][rg] = -1e30f;
        }

        // ---- P = exp2(S'), fused row-sum, pack 4 keys -> ds_write_b64 ----
        #pragma unroll
        for (int tt = 0; tt < 4; ++tt) {
            float p0, p1, p2, p3;
            asm("v_exp_f32 %0, %1" : "=v"(p0) : "v"(acc[tt][0]));
            asm("v_exp_f32 %0, %1" : "=v"(p1) : "v"(acc[tt][1]));
            asm("v_exp_f32 %0, %1" : "=v"(p2) : "v"(acc[tt][2]));
            asm("v_exp_f32 %0, %1" : "=v"(p3) : "v"(acc[tt][3]));
            Lsum += (p0 + p1) + (p2 + p3);
            half4 pk;
            pk[0] = (_Float16)p0; pk[1] = (_Float16)p1;
            pk[2] = (_Float16)p2; pk[3] = (_Float16)p3;
            // keys 16tt+4qd..+3, query n: contiguous 8B (block 2tt+(qd>>1))
            *(half4*)&Pw[n * 64 + ((2 * tt + (qd >> 1)) ^ (n & 7)) * 8 + (qd & 1) * 4] = pk;
        }

        // Ps is per-wave: drain DS writes only, no WG barrier.
        asm volatile("s_waitcnt lgkmcnt(0)" ::: "memory");

        // ---- O += P V ----
        __builtin_amdgcn_s_setprio(1);
        #pragma unroll
        for (int js = 0; js < 2; ++js) {
            half8 pf = *(const half8*)&Pw[n * 64 + (((js << 2) | qd) ^ (n & 7)) * 8];
            #pragma unroll
            for (int tt = 0; tt < 4; ++tt) {
                const int d = tt * 16 + n;
                half8 vf = *(const half8*)&Vt[d * 64 + (((js << 2) | qd) ^ (d & 7)) * 8];
                Oacc[tt] = __builtin_amdgcn_mfma_f32_16x16x32_f16(pf, vf, Oacc[tt], 0, 0, 0);
            }
        }
        __builtin_amdgcn_s_setprio(0);
    };

    // ---- prologue part 2: stage chunk cbeg, issue cbeg+1 (>=3 chunks) ----
    commitKV();                 // one exposed vmcnt wait per WG
    prefetchKV(cbeg + 1);
    WG_BARRIER();               // chunk cbeg visible; cbeg+1 loads in flight

    // ---- rolled main loop, single LDS buffer, 2 barriers/chunk ----
    #pragma unroll 1
    for (int c = cbeg; c <= cend; ++c) {
        compute(c);
        if (c < cend) {
            WG_BARRIER();                       // all waves done reading Ks/Vt
            commitKV();                         // chunk c+1 (loads in flight
                                                //  since before compute(c))
            if (c + 2 <= cend) prefetchKV(c + 2);
            WG_BARRIER();                       // chunk c+1 published
        }
    }

    // ---- epilogue: reduce l across quads, divide, store fp32 ----
    float lt = Lsum + __shfl_xor(Lsum, 16, 64);
    lt += __shfl_xor(lt, 32, 64);              // lanes sharing n: full L(query n)
    #pragma unroll
    for (int rg = 0; rg < 4; ++rg) {
        const float lr = __shfl(lt, qd * 4 + rg, 64);  // L for this output row
        const float inv = 1.0f / lr;
        float* op = Op + (size_t)(s + 16 * w + qd * 4 + rg) * 64 + n;
        op[0]  = Oacc[0][rg] * inv;
        op[16] = Oacc[1][rg] * inv;
        op[32] = Oacc[2][rg] * inv;
        op[48] = Oacc[3][rg] * inv;
    }
}

extern "C" void kernel_launch(void* const* d_in, const int* in_sizes, int n_in,
                              void* d_out, int out_size, void* d_ws, size_t ws_size,
                              hipStream_t stream) {
    const float* q = (const float*)d_in[0];
    const float* k = (const float*)d_in[1];
    const float* v = (const float*)d_in[2];
    float* o = (float*)d_out;
    dim3 grid(T_SEQ / 64, NH, 2);
    dim3 block(256);
    local_attn_f16<<<grid, block, 0, stream>>>(q, k, v, o);
}